// Round 3
// baseline (277.034 us; speedup 1.0000x reference)
//
#include <hip/hip_runtime.h>
#include <hip/hip_bf16.h>
#include <stdint.h>

// Problem constants
#define M_DIM 32768
#define N_DIM 1024
#define K_DIM 1024

using int32x4 = __attribute__((ext_vector_type(4))) int;

__device__ __forceinline__ void gload_lds16(const void* g, void* l) {
  __builtin_amdgcn_global_load_lds(
      (const __attribute__((address_space(1))) void*)g,
      (__attribute__((address_space(3))) void*)l,
      16 /*bytes*/, 0 /*offset*/, 0 /*aux*/);
}

// ---------------- Kernel 1: quantize fp32 activations -> int8 ----------------
// q = clip(round(x * 20.0), -127, 127)   (RNE to match jnp.round)
__global__ __launch_bounds__(256) void quant_kernel(const float* __restrict__ x,
                                                    uint32_t* __restrict__ q) {
  const int g = blockIdx.x * 256 + threadIdx.x;  // one float4 per thread
  const float4 v = ((const float4*)x)[g];
  int a0 = (int)rintf(fminf(fmaxf(v.x * 20.0f, -127.0f), 127.0f));
  int a1 = (int)rintf(fminf(fmaxf(v.y * 20.0f, -127.0f), 127.0f));
  int a2 = (int)rintf(fminf(fmaxf(v.z * 20.0f, -127.0f), 127.0f));
  int a3 = (int)rintf(fminf(fmaxf(v.w * 20.0f, -127.0f), 127.0f));
  q[g] = (uint32_t)(a0 & 0xFF) | ((uint32_t)(a1 & 0xFF) << 8) |
         ((uint32_t)(a2 & 0xFF) << 16) | ((uint32_t)(a3 & 0xFF) << 24);
}

// ---------------- Kernel 2: unpack int4 weights -> int8 [N, K] ----------------
// HARNESS NOTE: integer inputs arrive as int32 — weight_packed is 524288 int32
// elements, ONE packed byte (0..255) per int32. Byte j of row r: low nibble ->
// w[r][2j], high nibble -> w[r][2j+1].  sext4(v) = ((v&0xF)^8)-8.
__global__ __launch_bounds__(256) void unpack_kernel(const int4* __restrict__ wp,
                                                     uint2* __restrict__ w8) {
  const int g = blockIdx.x * 256 + threadIdx.x;  // 4 packed bytes -> 8 int8
  const int4 p = wp[g];
  int w0 = ((p.x & 0xF) ^ 8) - 8;
  int w1 = (((p.x >> 4) & 0xF) ^ 8) - 8;
  int w2 = ((p.y & 0xF) ^ 8) - 8;
  int w3 = (((p.y >> 4) & 0xF) ^ 8) - 8;
  int w4 = ((p.z & 0xF) ^ 8) - 8;
  int w5 = (((p.z >> 4) & 0xF) ^ 8) - 8;
  int w6 = ((p.w & 0xF) ^ 8) - 8;
  int w7 = (((p.w >> 4) & 0xF) ^ 8) - 8;
  uint2 st;
  st.x = (uint32_t)(w0 & 0xFF) | ((uint32_t)(w1 & 0xFF) << 8) |
         ((uint32_t)(w2 & 0xFF) << 16) | ((uint32_t)(w3 & 0xFF) << 24);
  st.y = (uint32_t)(w4 & 0xFF) | ((uint32_t)(w5 & 0xFF) << 8) |
         ((uint32_t)(w6 & 0xFF) << 16) | ((uint32_t)(w7 & 0xFF) << 24);
  w8[g] = st;
}

// ---------------- Kernel 3: int8 x int8 GEMM with dequant epilogue ----------------
// C[m][n] = (sum_k A[m][k] * W[n][k]) * (A_SCALE*W_SCALE) + bias[n], f32 out.
// 128x128 tile, BK=64, 4 waves in 2x2, mfma_i32_16x16x64_i8.
// LDS chunk swizzle: LDS[r][c] = G[r][c ^ ((r>>1)&3)] -> frag ds_read_b128 at 2-way (free).
__global__ __launch_bounds__(256) void gemm_kernel(const uint8_t* __restrict__ A,
                                                   const uint8_t* __restrict__ W,
                                                   const float* __restrict__ bias,
                                                   float* __restrict__ out) {
  __shared__ uint8_t sA[128 * 64];
  __shared__ uint8_t sB[128 * 64];

  const int tid = threadIdx.x;
  const int bx = blockIdx.x;
  const int n0 = (bx & 7) * 128;   // N/128 = 8 fastest -> concurrent blocks share A row-tile
  const int m0 = (bx >> 3) * 128;
  const int lane = tid & 63;
  const int wid = tid >> 6;
  const int wm = wid >> 1;
  const int wn = wid & 1;

  // Staging: 8 KB per tile = 512 chunks of 16 B; 256 threads x 2 chunks.
  // li = j*256 + tid; row r = li>>2; lds slot c = li&3; global chunk cg = c ^ ((r>>1)&3)
  const int li0 = tid, li1 = 256 + tid;
  const int r0 = li0 >> 2, c0 = li0 & 3;
  const int r1 = li1 >> 2, c1 = li1 & 3;
  const int cg0 = c0 ^ ((r0 >> 1) & 3);
  const int cg1 = c1 ^ ((r1 >> 1) & 3);
  const uint8_t* gA0 = A + (size_t)(m0 + r0) * K_DIM + cg0 * 16;
  const uint8_t* gA1 = A + (size_t)(m0 + r1) * K_DIM + cg1 * 16;
  const uint8_t* gB0 = W + (size_t)(n0 + r0) * K_DIM + cg0 * 16;
  const uint8_t* gB1 = W + (size_t)(n0 + r1) * K_DIM + cg1 * 16;
  uint8_t* lA0 = sA + li0 * 16;
  uint8_t* lA1 = sA + li1 * 16;
  uint8_t* lB0 = sB + li0 * 16;
  uint8_t* lB1 = sB + li1 * 16;

  int32x4 acc[4][4] = {};  // 64 accumulator regs

  const int q = lane >> 4;          // logical 16-byte chunk (k-quarter) for frags
  const int fr = lane & 15;         // row/col within 16-tile

  for (int kk = 0; kk < K_DIM; kk += 64) {
    gload_lds16(gA0 + kk, lA0);
    gload_lds16(gA1 + kk, lA1);
    gload_lds16(gB0 + kk, lB0);
    gload_lds16(gB1 + kk, lB1);
    __syncthreads();

    int32x4 af[4], bf[4];
#pragma unroll
    for (int mt = 0; mt < 4; mt++) {
      const int r = wm * 64 + mt * 16 + fr;
      const int cc = q ^ ((r >> 1) & 3);
      af[mt] = *(const int32x4*)(sA + r * 64 + cc * 16);
    }
#pragma unroll
    for (int nt = 0; nt < 4; nt++) {
      const int r = wn * 64 + nt * 16 + fr;
      const int cc = q ^ ((r >> 1) & 3);
      bf[nt] = *(const int32x4*)(sB + r * 64 + cc * 16);
    }
#pragma unroll
    for (int mt = 0; mt < 4; mt++)
#pragma unroll
      for (int nt = 0; nt < 4; nt++)
        acc[mt][nt] = __builtin_amdgcn_mfma_i32_16x16x64_i8(af[mt], bf[nt], acc[mt][nt], 0, 0, 0);
    __syncthreads();
  }

  // Epilogue: C/D layout col = lane&15, row = (lane>>4)*4 + reg
  float bv[4];
#pragma unroll
  for (int nt = 0; nt < 4; nt++) bv[nt] = bias[n0 + wn * 64 + nt * 16 + fr];

  const int rowq = (lane >> 4) * 4;
#pragma unroll
  for (int mt = 0; mt < 4; mt++) {
#pragma unroll
    for (int nt = 0; nt < 4; nt++) {
      const int n_g = n0 + wn * 64 + nt * 16 + fr;
#pragma unroll
      for (int r = 0; r < 4; r++) {
        const int m_g = m0 + wm * 64 + mt * 16 + rowq + r;
        const float v = (float)acc[mt][nt][r] * 0.0005f + bv[nt];
        out[(size_t)m_g * N_DIM + n_g] = v;
      }
    }
  }
}

extern "C" void kernel_launch(void* const* d_in, const int* in_sizes, int n_in,
                              void* d_out, int out_size, void* d_ws, size_t ws_size,
                              hipStream_t stream) {
  const float* x = (const float*)d_in[0];
  const int4* wp = (const int4*)d_in[1];   // int32 per packed byte (harness int rule)
  const float* bias = (const float*)d_in[2];
  float* out = (float*)d_out;

  uint8_t* A8 = (uint8_t*)d_ws;                       // 32768*1024 int8 = 32 MiB
  uint8_t* W8 = A8 + (size_t)M_DIM * K_DIM;           // 1024*1024 int8 = 1 MiB

  // K1: quantize activations. 33.5M elems / 4 per thread / 256 per block
  quant_kernel<<<(M_DIM * K_DIM) / (4 * 256), 256, 0, stream>>>(x, (uint32_t*)A8);
  // K2: unpack weights. 524288 int32 elems / 4 per thread / 256 per block
  unpack_kernel<<<(N_DIM * K_DIM / 2) / (4 * 256), 256, 0, stream>>>(wp, (uint2*)W8);
  // K3: GEMM. grid = (M/128)*(N/128) = 2048
  gemm_kernel<<<(M_DIM / 128) * (N_DIM / 128), 256, 0, stream>>>(A8, W8, bias, out);
}